// Round 1
// baseline (1000.018 us; speedup 1.0000x reference)
//
#include <hip/hip_runtime.h>
#include <hip/hip_bf16.h>

#define NN 100000
#define MM 32
#define NCAPS_ 8
#define HH 64
#define FAN 512  // NCAPS*H

typedef __attribute__((ext_vector_type(8))) short bf16x8;
typedef __attribute__((ext_vector_type(4))) float f32x4;

__device__ inline short f2bf(float f) {
  union { float f; unsigned u; } v; v.f = f;
  unsigned u = v.u;
  u += 0x7FFFu + ((u >> 16) & 1u);   // round-to-nearest-even
  return (short)(u >> 16);
}

__device__ inline bf16x8 cvt8(f32x4 lo, f32x4 hi) {
  bf16x8 r;
  r[0] = f2bf(lo[0]); r[1] = f2bf(lo[1]); r[2] = f2bf(lo[2]); r[3] = f2bf(lo[3]);
  r[4] = f2bf(hi[0]); r[5] = f2bf(hi[1]); r[6] = f2bf(hi[2]); r[7] = f2bf(hi[3]);
  return r;
}

// ---------------------------------------------------------------------------
// Kernel A: per-node aggregation.  One wave (64 lanes) per node.
// lane = feature dim within H=64.  rel / nbr are wave-uniform per edge.
// v[n, r, l] = x[n, r, l] + sum_{edges e of n with rel==r} x[nbr_e, r, l]
// ---------------------------------------------------------------------------
__global__ __launch_bounds__(256) void agg_kernel(
    const float* __restrict__ x,
    const int* __restrict__ nb_node,
    const int* __restrict__ nb_rel,
    float* __restrict__ v) {
  const int gid  = blockIdx.x * blockDim.x + threadIdx.x;
  const int node = gid >> 6;
  const int lane = threadIdx.x & 63;
  if (node >= NN) return;

  float acc[NCAPS_];
#pragma unroll
  for (int r = 0; r < NCAPS_; ++r) acc[r] = 0.f;

  const int base = node * MM;
#pragma unroll 8
  for (int e = 0; e < MM; ++e) {
    int nb = nb_node[base + e];
    int rl = nb_rel[base + e];
    nb = __builtin_amdgcn_readfirstlane(nb);
    rl = __builtin_amdgcn_readfirstlane(rl);
    // unconditional (clamped) load so it can pipeline; zero if nbr == NN
    const int nbc = (nb < NN) ? nb : node;
    float val = x[(size_t)nbc * FAN + rl * HH + lane];
    val = (nb < NN) ? val : 0.f;
    switch (rl) {
      case 0: acc[0] += val; break;
      case 1: acc[1] += val; break;
      case 2: acc[2] += val; break;
      case 3: acc[3] += val; break;
      case 4: acc[4] += val; break;
      case 5: acc[5] += val; break;
      case 6: acc[6] += val; break;
      case 7: acc[7] += val; break;
    }
  }

  const size_t o = (size_t)node * FAN + lane;
#pragma unroll
  for (int r = 0; r < NCAPS_; ++r)
    v[o + r * HH] = acc[r] + x[o + r * HH];
}

// ---------------------------------------------------------------------------
// Kernel B: out = relu(v @ W^T + b), in place on d_out.
// Block = 256 threads = 4 waves.  BM=64 rows per block; wave w owns cols
// [w*128, (w+1)*128).  mfma_f32_16x16x32_bf16:
//   A: lane holds A[lane&15][8*(lane>>4)+i], i=0..7
//   B: lane holds B[8*(lane>>4)+i][lane&15]
//   D: col = lane&15, row = (lane>>4)*4 + reg       (guide §3, m89-verified)
// B[k][j] = W[j][k]  (row-major W → 32B contiguous per-lane loads)
// ---------------------------------------------------------------------------
__global__ __launch_bounds__(256) void gemm_kernel(
    const float* vin,                 // [NN][FAN]  (aliases out)
    const float* __restrict__ W,     // [FAN][FAN]
    const float* __restrict__ bias,  // [FAN]
    float* out) {
  const int lane = threadIdx.x & 63;
  const int wave = threadIdx.x >> 6;
  const int row0 = blockIdx.x * 64;
  const int col0 = wave * 128;
  const int l15  = lane & 15;
  const int kg   = lane >> 4;  // 0..3

  f32x4 acc[4][8];
#pragma unroll
  for (int rf = 0; rf < 4; ++rf)
#pragma unroll
    for (int c = 0; c < 8; ++c) acc[rf][c] = (f32x4){0.f, 0.f, 0.f, 0.f};

  for (int kb = 0; kb < FAN / 32; ++kb) {
    const int k0 = kb * 32 + kg * 8;

    bf16x8 afrag[4];
#pragma unroll
    for (int rf = 0; rf < 4; ++rf) {
      int row = row0 + rf * 16 + l15;
      if (row >= NN) row = NN - 1;              // clamp (store is guarded)
      const float* p = vin + (size_t)row * FAN + k0;
      f32x4 lo = *(const f32x4*)(p);
      f32x4 hi = *(const f32x4*)(p + 4);
      afrag[rf] = cvt8(lo, hi);
    }

#pragma unroll
    for (int c = 0; c < 8; ++c) {
      const int col = col0 + c * 16 + l15;
      const float* q = W + (size_t)col * FAN + k0;
      f32x4 lo = *(const f32x4*)(q);
      f32x4 hi = *(const f32x4*)(q + 4);
      bf16x8 bfrag = cvt8(lo, hi);
#pragma unroll
      for (int rf = 0; rf < 4; ++rf)
        acc[rf][c] = __builtin_amdgcn_mfma_f32_16x16x32_bf16(
            afrag[rf], bfrag, acc[rf][c], 0, 0, 0);
    }
  }

  // epilogue: bias + relu + store
#pragma unroll
  for (int c = 0; c < 8; ++c) {
    const int col = col0 + c * 16 + l15;
    const float bb = bias[col];
#pragma unroll
    for (int rf = 0; rf < 4; ++rf) {
#pragma unroll
      for (int r = 0; r < 4; ++r) {
        const int row = row0 + rf * 16 + kg * 4 + r;
        if (row < NN) {
          float val = acc[rf][c][r] + bb;
          out[(size_t)row * FAN + col] = val > 0.f ? val : 0.f;
        }
      }
    }
  }
}

extern "C" void kernel_launch(void* const* d_in, const int* in_sizes, int n_in,
                              void* d_out, int out_size, void* d_ws, size_t ws_size,
                              hipStream_t stream) {
  const float* x  = (const float*)d_in[0];
  const float* W  = (const float*)d_in[1];
  const float* b  = (const float*)d_in[2];
  const int*   nn = (const int*)d_in[3];
  const int*   nr = (const int*)d_in[4];
  float* out = (float*)d_out;

  // Kernel A: v = agg + x  -> d_out (f32).  100000 waves, 4 per block.
  agg_kernel<<<(NN * 64) / 256, 256, 0, stream>>>(x, nn, nr, out);

  // Kernel B: out = relu(v @ W^T + b), in place (block owns its 64 rows).
  gemm_kernel<<<(NN + 63) / 64, 256, 0, stream>>>(out, W, b, out);
}

// Round 2
// 689.869 us; speedup vs baseline: 1.4496x; 1.4496x over previous
//
#include <hip/hip_runtime.h>
#include <hip/hip_bf16.h>

#define NN 100000
#define MM 32
#define NCAPS_ 8
#define HH 64
#define FAN 512  // NCAPS*H

typedef __attribute__((ext_vector_type(8))) short bf16x8;
typedef __attribute__((ext_vector_type(4))) float f32x4;

__device__ inline short f2bf(float f) {
  union { float f; unsigned u; } v; v.f = f;
  unsigned u = v.u;
  u += 0x7FFFu + ((u >> 16) & 1u);   // round-to-nearest-even
  return (short)(u >> 16);
}

__device__ inline bf16x8 cvt8(f32x4 lo, f32x4 hi) {
  bf16x8 r;
  r[0] = f2bf(lo[0]); r[1] = f2bf(lo[1]); r[2] = f2bf(lo[2]); r[3] = f2bf(lo[3]);
  r[4] = f2bf(hi[0]); r[5] = f2bf(hi[1]); r[6] = f2bf(hi[2]); r[7] = f2bf(hi[3]);
  return r;
}

// ---------------------------------------------------------------------------
// W f32 -> bf16 (once).  262144 elems, 8 per thread.
// ---------------------------------------------------------------------------
__global__ __launch_bounds__(256) void wconv_kernel(
    const float* __restrict__ W, short* __restrict__ Wbf) {
  const int i = (blockIdx.x * 256 + threadIdx.x) * 8;
  f32x4 lo = *(const f32x4*)(W + i);
  f32x4 hi = *(const f32x4*)(W + i + 4);
  *(bf16x8*)(Wbf + i) = cvt8(lo, hi);
}

// ---------------------------------------------------------------------------
// Kernel A: per-node aggregation, one wave per node, lane = dim within H=64.
// v_bf16[n, r, l] = bf16( x[n,r,l] + sum_{edges e: rel==r} x[nbr_e, r, l] )
// Edge indices are wave-uniform -> scalar loads; 32-deep unroll for gather ILP.
// ---------------------------------------------------------------------------
template <bool BF16OUT>
__global__ __launch_bounds__(256) void agg_kernel(
    const float* __restrict__ x,
    const int* __restrict__ nb_node,
    const int* __restrict__ nb_rel,
    short* __restrict__ vbf,    // used if BF16OUT
    float* __restrict__ vf32) { // used if !BF16OUT
  const int gid  = blockIdx.x * blockDim.x + threadIdx.x;
  const int node = gid >> 6;
  const int lane = threadIdx.x & 63;
  if (node >= NN) return;

  float acc[NCAPS_];
#pragma unroll
  for (int r = 0; r < NCAPS_; ++r) acc[r] = 0.f;

  const int base = node * MM;
#pragma unroll
  for (int e = 0; e < MM; ++e) {
    int nb = __builtin_amdgcn_readfirstlane(nb_node[base + e]);
    int rl = __builtin_amdgcn_readfirstlane(nb_rel[base + e]);
    const int nbc = (nb < NN) ? nb : node;   // clamped load, zeroed below
    float val = x[(size_t)nbc * FAN + rl * HH + lane];
    val = (nb < NN) ? val : 0.f;
    switch (rl) {
      case 0: acc[0] += val; break;
      case 1: acc[1] += val; break;
      case 2: acc[2] += val; break;
      case 3: acc[3] += val; break;
      case 4: acc[4] += val; break;
      case 5: acc[5] += val; break;
      case 6: acc[6] += val; break;
      case 7: acc[7] += val; break;
    }
  }

  const size_t o = (size_t)node * FAN + lane;
#pragma unroll
  for (int r = 0; r < NCAPS_; ++r) {
    float res = acc[r] + x[o + r * HH];
    if (BF16OUT) vbf[o + r * HH] = f2bf(res);
    else         vf32[o + r * HH] = res;
  }
}

// ---------------------------------------------------------------------------
// Kernel B (fast path): out = relu(v_bf16 @ Wbf^T + b).  Pure bf16 loads,
// no in-loop conversion.  Block = 4 waves, BM=64 rows, wave owns 128 cols.
// mfma_f32_16x16x32_bf16: D col = lane&15, row = (lane>>4)*4 + reg.
// ---------------------------------------------------------------------------
__global__ __launch_bounds__(256) void gemm_bf_kernel(
    const short* __restrict__ vbf,   // [NN][FAN] bf16
    const short* __restrict__ Wbf,   // [FAN][FAN] bf16 (row-major W)
    const float* __restrict__ bias,  // [FAN]
    float* __restrict__ out) {
  const int lane = threadIdx.x & 63;
  const int wave = threadIdx.x >> 6;
  const int row0 = blockIdx.x * 64;
  const int col0 = wave * 128;
  const int l15  = lane & 15;
  const int kg   = lane >> 4;  // 0..3

  f32x4 acc[4][8];
#pragma unroll
  for (int rf = 0; rf < 4; ++rf)
#pragma unroll
    for (int c = 0; c < 8; ++c) acc[rf][c] = (f32x4){0.f, 0.f, 0.f, 0.f};

  for (int kb = 0; kb < FAN / 32; ++kb) {
    const int k0 = kb * 32 + kg * 8;

    bf16x8 afrag[4];
#pragma unroll
    for (int rf = 0; rf < 4; ++rf) {
      int row = row0 + rf * 16 + l15;
      if (row >= NN) row = NN - 1;             // clamp (store is guarded)
      afrag[rf] = *(const bf16x8*)(vbf + (size_t)row * FAN + k0);
    }

#pragma unroll
    for (int c = 0; c < 8; ++c) {
      const int col = col0 + c * 16 + l15;
      bf16x8 bfrag = *(const bf16x8*)(Wbf + (size_t)col * FAN + k0);
#pragma unroll
      for (int rf = 0; rf < 4; ++rf)
        acc[rf][c] = __builtin_amdgcn_mfma_f32_16x16x32_bf16(
            afrag[rf], bfrag, acc[rf][c], 0, 0, 0);
    }
  }

#pragma unroll
  for (int c = 0; c < 8; ++c) {
    const int col = col0 + c * 16 + l15;
    const float bb = bias[col];
#pragma unroll
    for (int rf = 0; rf < 4; ++rf) {
#pragma unroll
      for (int r = 0; r < 4; ++r) {
        const int row = row0 + rf * 16 + kg * 4 + r;
        if (row < NN) {
          float val = acc[rf][c][r] + bb;
          out[(size_t)row * FAN + col] = val > 0.f ? val : 0.f;
        }
      }
    }
  }
}

// ---------------------------------------------------------------------------
// Kernel B (fallback, round-1 style): f32 inputs, in-loop conversion.
// ---------------------------------------------------------------------------
__global__ __launch_bounds__(256) void gemm_f32_kernel(
    const float* vin, const float* __restrict__ W,
    const float* __restrict__ bias, float* out) {
  const int lane = threadIdx.x & 63;
  const int wave = threadIdx.x >> 6;
  const int row0 = blockIdx.x * 64;
  const int col0 = wave * 128;
  const int l15  = lane & 15;
  const int kg   = lane >> 4;

  f32x4 acc[4][8];
#pragma unroll
  for (int rf = 0; rf < 4; ++rf)
#pragma unroll
    for (int c = 0; c < 8; ++c) acc[rf][c] = (f32x4){0.f, 0.f, 0.f, 0.f};

  for (int kb = 0; kb < FAN / 32; ++kb) {
    const int k0 = kb * 32 + kg * 8;
    bf16x8 afrag[4];
#pragma unroll
    for (int rf = 0; rf < 4; ++rf) {
      int row = row0 + rf * 16 + l15;
      if (row >= NN) row = NN - 1;
      const float* p = vin + (size_t)row * FAN + k0;
      afrag[rf] = cvt8(*(const f32x4*)p, *(const f32x4*)(p + 4));
    }
#pragma unroll
    for (int c = 0; c < 8; ++c) {
      const int col = col0 + c * 16 + l15;
      const float* q = W + (size_t)col * FAN + k0;
      bf16x8 bfrag = cvt8(*(const f32x4*)q, *(const f32x4*)(q + 4));
#pragma unroll
      for (int rf = 0; rf < 4; ++rf)
        acc[rf][c] = __builtin_amdgcn_mfma_f32_16x16x32_bf16(
            afrag[rf], bfrag, acc[rf][c], 0, 0, 0);
    }
  }

#pragma unroll
  for (int c = 0; c < 8; ++c) {
    const int col = col0 + c * 16 + l15;
    const float bb = bias[col];
#pragma unroll
    for (int rf = 0; rf < 4; ++rf)
#pragma unroll
      for (int r = 0; r < 4; ++r) {
        const int row = row0 + rf * 16 + kg * 4 + r;
        if (row < NN) {
          float val = acc[rf][c][r] + bb;
          out[(size_t)row * FAN + col] = val > 0.f ? val : 0.f;
        }
      }
  }
}

extern "C" void kernel_launch(void* const* d_in, const int* in_sizes, int n_in,
                              void* d_out, int out_size, void* d_ws, size_t ws_size,
                              hipStream_t stream) {
  const float* x  = (const float*)d_in[0];
  const float* W  = (const float*)d_in[1];
  const float* b  = (const float*)d_in[2];
  const int*   nn = (const int*)d_in[3];
  const int*   nr = (const int*)d_in[4];
  float* out = (float*)d_out;

  const size_t wbf_bytes = (size_t)FAN * FAN * sizeof(short);        // 512 KB
  const size_t vbf_bytes = (size_t)NN * FAN * sizeof(short);         // 102.4 MB
  const bool fast = ws_size >= wbf_bytes + vbf_bytes;

  if (fast) {
    short* Wbf = (short*)d_ws;
    short* vbf = (short*)((char*)d_ws + wbf_bytes);
    wconv_kernel<<<FAN * FAN / (256 * 8), 256, 0, stream>>>(W, Wbf);
    agg_kernel<true><<<(NN * 64) / 256, 256, 0, stream>>>(x, nn, nr, vbf, nullptr);
    gemm_bf_kernel<<<(NN + 63) / 64, 256, 0, stream>>>(vbf, Wbf, b, out);
  } else {
    agg_kernel<false><<<(NN * 64) / 256, 256, 0, stream>>>(x, nn, nr, nullptr, out);
    gemm_f32_kernel<<<(NN + 63) / 64, 256, 0, stream>>>(out, W, b, out);
  }
}

// Round 3
// 305.983 us; speedup vs baseline: 3.2682x; 2.2546x over previous
//
#include <hip/hip_runtime.h>
#include <hip/hip_bf16.h>

#define NN 100000
#define MM 32
#define NCAPS_ 8
#define HH 64
#define FAN 512  // NCAPS*H

typedef __attribute__((ext_vector_type(8))) short bf16x8;
typedef __attribute__((ext_vector_type(4))) float f32x4;

__device__ inline short f2bf(float f) {
  union { float f; unsigned u; } v; v.f = f;
  unsigned u = v.u;
  u += 0x7FFFu + ((u >> 16) & 1u);   // round-to-nearest-even
  return (short)(u >> 16);
}

__device__ inline bf16x8 cvt8(f32x4 lo, f32x4 hi) {
  bf16x8 r;
  r[0] = f2bf(lo[0]); r[1] = f2bf(lo[1]); r[2] = f2bf(lo[2]); r[3] = f2bf(lo[3]);
  r[4] = f2bf(hi[0]); r[5] = f2bf(hi[1]); r[6] = f2bf(hi[2]); r[7] = f2bf(hi[3]);
  return r;
}

// ---------------------------------------------------------------------------
// W f32 -> bf16 (once).  262144 elems, 8 per thread.
// ---------------------------------------------------------------------------
__global__ __launch_bounds__(256) void wconv_kernel(
    const float* __restrict__ W, short* __restrict__ Wbf) {
  const int i = (blockIdx.x * 256 + threadIdx.x) * 8;
  f32x4 lo = *(const f32x4*)(W + i);
  f32x4 hi = *(const f32x4*)(W + i + 4);
  *(bf16x8*)(Wbf + i) = cvt8(lo, hi);
}

// ---------------------------------------------------------------------------
// Kernel A: per-node aggregation, one wave per node, lane = dim within H=64.
// Phase 0: ONE vector load of all 32 (node,rel) index pairs + readlane bcast.
// Phase 1: issue all 32 gathers back-to-back into distinct VGPRs (32-deep MLP)
//          + the 8 residual loads.  NO dependent ops between loads.
// Phase 2: masked select + rel-switch accumulate (waits drain in order).
// ---------------------------------------------------------------------------
template <bool BF16OUT>
__global__ __launch_bounds__(256) void agg_kernel(
    const float* __restrict__ x,
    const int* __restrict__ nb_node,
    const int* __restrict__ nb_rel,
    short* __restrict__ vbf,
    float* __restrict__ vf32) {
  const int gid  = blockIdx.x * blockDim.x + threadIdx.x;
  const int node = gid >> 6;
  const int lane = threadIdx.x & 63;
  if (node >= NN) return;

  const int base = node * MM;

  // phase 0: indices (one load for all edges, lanes 32..63 duplicate 0..31)
  const int eidx = base + (lane & 31);
  const int my_nb = nb_node[eidx];
  const int my_rl = nb_rel[eidx];

  int nbs[MM], rls[MM];
  unsigned ok = 0;
#pragma unroll
  for (int e = 0; e < MM; ++e) {
    nbs[e] = __builtin_amdgcn_readlane(my_nb, e);
    rls[e] = __builtin_amdgcn_readlane(my_rl, e);
    if (nbs[e] < NN) ok |= (1u << e);
  }

  // phase 1: issue all gathers (clamped; zeroed in phase 2) + residuals
  float vals[MM];
#pragma unroll
  for (int e = 0; e < MM; ++e) {
    const int nbc = (nbs[e] < NN) ? nbs[e] : node;
    vals[e] = x[(size_t)nbc * FAN + rls[e] * HH + lane];
  }
  float xr[NCAPS_];
  const size_t o = (size_t)node * FAN + lane;
#pragma unroll
  for (int r = 0; r < NCAPS_; ++r) xr[r] = x[o + r * HH];

  // phase 2: accumulate
  float acc[NCAPS_];
#pragma unroll
  for (int r = 0; r < NCAPS_; ++r) acc[r] = 0.f;
#pragma unroll
  for (int e = 0; e < MM; ++e) {
    float val = ((ok >> e) & 1u) ? vals[e] : 0.f;
    switch (rls[e]) {
      case 0: acc[0] += val; break;
      case 1: acc[1] += val; break;
      case 2: acc[2] += val; break;
      case 3: acc[3] += val; break;
      case 4: acc[4] += val; break;
      case 5: acc[5] += val; break;
      case 6: acc[6] += val; break;
      case 7: acc[7] += val; break;
    }
  }

#pragma unroll
  for (int r = 0; r < NCAPS_; ++r) {
    float res = acc[r] + xr[r];
    if (BF16OUT) vbf[o + r * HH] = f2bf(res);
    else         vf32[o + r * HH] = res;
  }
}

// ---------------------------------------------------------------------------
// Kernel B: out = relu(vbf @ Wbf^T + b).  m97-style: 128x128 tile, BK=32,
// double-buffered global_load_lds staging, ds_read_b128 frags, 4 waves each
// owning a 64x64 quadrant (4x4 16x16x32 MFMA frags).
// LDS layout [row][32 bf16] (64B rows): frag-read slot = (row*4+kg)&7 is
// uniform over the wave -> conflict-free b128 reads, no swizzle needed.
// ---------------------------------------------------------------------------
#define BM 128
#define BN 128
#define BK 32
#define NRB ((NN + BM - 1) / BM)  // 782

__global__ __launch_bounds__(256) void gemm_bf_kernel(
    const short* __restrict__ vbf,   // [NN][FAN] bf16
    const short* __restrict__ Wbf,   // [FAN][FAN] bf16 (row-major W)
    const float* __restrict__ bias,
    float* __restrict__ out) {
  __shared__ short Ab[2][BM * BK];
  __shared__ short Bb[2][BN * BK];

  const int tid  = threadIdx.x;
  const int lane = tid & 63;
  const int wave = tid >> 6;
  const int wr = wave >> 1, wc = wave & 1;
  const int l15 = lane & 15, kg = lane >> 4;

  const int rb = blockIdx.x % NRB;
  const int cb = blockIdx.x / NRB;
  const int row0 = rb * BM, col0 = cb * BN;

  f32x4 acc[4][4];
#pragma unroll
  for (int rf = 0; rf < 4; ++rf)
#pragma unroll
    for (int cf = 0; cf < 4; ++cf) acc[rf][cf] = (f32x4){0.f, 0.f, 0.f, 0.f};

  auto stage = [&](int buf, int kb) {
#pragma unroll
    for (int c = 0; c < 2; ++c) {
      const int byteoff = c * 4096 + tid * 16;
      int arow = row0 + (byteoff >> 6);
      if (arow >= NN) arow = NN - 1;                    // clamp (store guarded)
      const char* asrc = (const char*)vbf + (size_t)arow * 1024 + kb * 64 + (byteoff & 63);
      char* adst = (char*)(&Ab[buf][0]) + byteoff;
      __builtin_amdgcn_global_load_lds(
          (const __attribute__((address_space(1))) void*)asrc,
          (__attribute__((address_space(3))) void*)adst, 16, 0, 0);
      const int bcol = col0 + (byteoff >> 6);
      const char* bsrc = (const char*)Wbf + (size_t)bcol * 1024 + kb * 64 + (byteoff & 63);
      char* bdst = (char*)(&Bb[buf][0]) + byteoff;
      __builtin_amdgcn_global_load_lds(
          (const __attribute__((address_space(1))) void*)bsrc,
          (__attribute__((address_space(3))) void*)bdst, 16, 0, 0);
    }
  };

  stage(0, 0);
  __syncthreads();

  int buf = 0;
  for (int kb = 0; kb < FAN / BK; ++kb) {
    if (kb + 1 < FAN / BK) stage(buf ^ 1, kb + 1);

    bf16x8 af[4], bfr[4];
#pragma unroll
    for (int rf = 0; rf < 4; ++rf)
      af[rf] = *(const bf16x8*)(&Ab[buf][(wr * 64 + rf * 16 + l15) * BK + kg * 8]);
#pragma unroll
    for (int cf = 0; cf < 4; ++cf)
      bfr[cf] = *(const bf16x8*)(&Bb[buf][(wc * 64 + cf * 16 + l15) * BK + kg * 8]);

#pragma unroll
    for (int rf = 0; rf < 4; ++rf)
#pragma unroll
      for (int cf = 0; cf < 4; ++cf)
        acc[rf][cf] = __builtin_amdgcn_mfma_f32_16x16x32_bf16(
            af[rf], bfr[cf], acc[rf][cf], 0, 0, 0);

    __syncthreads();   // drains vmcnt (stage) + lgkmcnt; next iter reads buf^1
    buf ^= 1;
  }

  // epilogue: bias + relu + store.  D: col=l15, row=kg*4+r within frag.
#pragma unroll
  for (int cf = 0; cf < 4; ++cf) {
    const int col = col0 + wc * 64 + cf * 16 + l15;
    const float bb = bias[col];
#pragma unroll
    for (int rf = 0; rf < 4; ++rf) {
#pragma unroll
      for (int r = 0; r < 4; ++r) {
        const int row = row0 + wr * 64 + rf * 16 + kg * 4 + r;
        if (row < NN) {
          float val = acc[rf][cf][r] + bb;
          out[(size_t)row * FAN + col] = val > 0.f ? val : 0.f;
        }
      }
    }
  }
}

// ---------------------------------------------------------------------------
// Fallback GEMM (f32 inputs, in-loop conversion) if ws too small.
// ---------------------------------------------------------------------------
__global__ __launch_bounds__(256) void gemm_f32_kernel(
    const float* vin, const float* __restrict__ W,
    const float* __restrict__ bias, float* out) {
  const int lane = threadIdx.x & 63;
  const int wave = threadIdx.x >> 6;
  const int row0 = blockIdx.x * 64;
  const int col0 = wave * 128;
  const int l15  = lane & 15;
  const int kg   = lane >> 4;

  f32x4 acc[4][8];
#pragma unroll
  for (int rf = 0; rf < 4; ++rf)
#pragma unroll
    for (int c = 0; c < 8; ++c) acc[rf][c] = (f32x4){0.f, 0.f, 0.f, 0.f};

  for (int kb = 0; kb < FAN / 32; ++kb) {
    const int k0 = kb * 32 + kg * 8;
    bf16x8 afrag[4];
#pragma unroll
    for (int rf = 0; rf < 4; ++rf) {
      int row = row0 + rf * 16 + l15;
      if (row >= NN) row = NN - 1;
      const float* p = vin + (size_t)row * FAN + k0;
      afrag[rf] = cvt8(*(const f32x4*)p, *(const f32x4*)(p + 4));
    }
#pragma unroll
    for (int c = 0; c < 8; ++c) {
      const int col = col0 + c * 16 + l15;
      const float* q = W + (size_t)col * FAN + k0;
      bf16x8 bfrag = cvt8(*(const f32x4*)q, *(const f32x4*)(q + 4));
#pragma unroll
      for (int rf = 0; rf < 4; ++rf)
        acc[rf][c] = __builtin_amdgcn_mfma_f32_16x16x32_bf16(
            afrag[rf], bfrag, acc[rf][c], 0, 0, 0);
    }
  }

#pragma unroll
  for (int c = 0; c < 8; ++c) {
    const int col = col0 + c * 16 + l15;
    const float bb = bias[col];
#pragma unroll
    for (int rf = 0; rf < 4; ++rf)
#pragma unroll
      for (int r = 0; r < 4; ++r) {
        const int row = row0 + rf * 16 + kg * 4 + r;
        if (row < NN) {
          float val = acc[rf][c][r] + bb;
          out[(size_t)row * FAN + col] = val > 0.f ? val : 0.f;
        }
      }
  }
}

extern "C" void kernel_launch(void* const* d_in, const int* in_sizes, int n_in,
                              void* d_out, int out_size, void* d_ws, size_t ws_size,
                              hipStream_t stream) {
  const float* x  = (const float*)d_in[0];
  const float* W  = (const float*)d_in[1];
  const float* b  = (const float*)d_in[2];
  const int*   nn = (const int*)d_in[3];
  const int*   nr = (const int*)d_in[4];
  float* out = (float*)d_out;

  const size_t wbf_bytes = (size_t)FAN * FAN * sizeof(short);        // 512 KB
  const size_t vbf_bytes = (size_t)NN * FAN * sizeof(short);         // 102.4 MB
  const bool fast = ws_size >= wbf_bytes + vbf_bytes;

  if (fast) {
    short* Wbf = (short*)d_ws;
    short* vbf = (short*)((char*)d_ws + wbf_bytes);
    wconv_kernel<<<FAN * FAN / (256 * 8), 256, 0, stream>>>(W, Wbf);
    agg_kernel<true><<<(NN * 64) / 256, 256, 0, stream>>>(x, nn, nr, vbf, nullptr);
    gemm_bf_kernel<<<NRB * (FAN / BN), 256, 0, stream>>>(vbf, Wbf, b, out);
  } else {
    agg_kernel<false><<<(NN * 64) / 256, 256, 0, stream>>>(x, nn, nr, nullptr, out);
    gemm_f32_kernel<<<(NN + 63) / 64, 256, 0, stream>>>(out, W, b, out);
  }
}